// Round 12
// baseline (87.333 us; speedup 1.0000x reference)
//
#include <hip/hip_runtime.h>

typedef __attribute__((ext_vector_type(8))) short short8;
typedef __attribute__((ext_vector_type(4))) float f32x4;

namespace {
constexpr long long OFF_CODES = 4194304;        // 8*128*4096
constexpr long long OFF_LOSS  = 4227072;        // + 8*4096
constexpr long long OFF_DIST  = 4227073;
constexpr float EPS = 5e-4f;                    // > 2*max bf16-product dist err
// ws byte offsets
constexpr size_t WS_LACC = 0;                   // f64
constexpr size_t WS_WCNT = 8;                   // u32 worklist count
constexpr size_t WS_SCF  = 1024;                // 1024 f32
constexpr size_t WS_SZF  = 8192;                // 32768 f32 (ends 139264)
constexpr size_t WS_WLST = 139264;              // 32768 u32 (ends 270336)
constexpr size_t WS_CBF  = 270336;              // 1024*128 u16 frag-ordered (ends 532480)
}

__device__ __forceinline__ unsigned short bf_rne(float v) {
  unsigned int u = __float_as_uint(v);
  unsigned int r = u + 0x7FFFu + ((u >> 16) & 1u);
  return (unsigned short)(r >> 16);
}

// ---- prep: codebook -> fragment-ordered bf16 + f32 norms; zero lacc/wcnt ----
__global__ __launch_bounds__(256) void vq_cbfrag(
    const float* __restrict__ cb, unsigned short* __restrict__ cbf,
    float* __restrict__ scf, double* lacc, unsigned int* wcnt)
{
  __shared__ double pn[4][16];
  const int g = blockIdx.x;
  const int tid = threadIdx.x;
  const int ks = tid >> 6, l = tid & 63, lg = l >> 4, lj = l & 15;
  const float* src = cb + (size_t)(g * 16 + lj) * 128 + ks * 32 + lg * 8;
  double s = 0.0;
  short8 h;
#pragma unroll
  for (int e = 0; e < 8; ++e) {
    float v = src[e];
    float q = v * v;                             // f32 square (numpy chain)
    s += (double)q;
    h[e] = (short)bf_rne(v);
  }
  *reinterpret_cast<short8*>(cbf + (size_t)g * 2048 + (size_t)tid * 8) = h;
  s += __shfl_xor(s, 16);                        // reduce over lg (same lj)
  s += __shfl_xor(s, 32);
  if (lg == 0) pn[ks][lj] = s;
  __syncthreads();
  if (tid < 16)
    scf[g * 16 + tid] = (float)(pn[0][tid] + pn[1][tid] + pn[2][tid] + pn[3][tid]);
  if (blockIdx.x == 0 && tid == 0) { *lacc = 0.0; *wcnt = 0u; }
}

// ---- z row norms (f64 of f32 squares), streaming — fastest measured (r7) ----
__global__ __launch_bounds__(256) void vq_szf(
    const float* __restrict__ z, float* __restrict__ szf)
{
  __shared__ double pn[64][4];
  const int tid = threadIdx.x;
  const int R0 = blockIdx.x * 64;
  const int b = R0 >> 12, t0 = R0 & 4095;
  const int t = tid & 63, dg = tid >> 6;
  const float* zp = z + (size_t)b * 524288 + (size_t)dg * 32 * 4096 + t0 + t;
  double s = 0.0;
#pragma unroll
  for (int d = 0; d < 32; ++d) {
    float v = zp[(size_t)d * 4096];
    float q = v * v;
    s += (double)q;
  }
  pn[t][dg] = s;
  __syncthreads();
  if (tid < 64)
    szf[R0 + tid] = (float)(pn[tid][0] + pn[tid][1] + pn[tid][2] + pn[tid][3]);
}

// ---- main (r7-proven): 32 rows x 1024 j; dist + argmin + worklist ----
__global__ __launch_bounds__(256, 4) void vq_main(
    const float* __restrict__ z, const unsigned short* __restrict__ cbf,
    const float* __restrict__ scf, const float* __restrict__ szf,
    unsigned int* __restrict__ wcnt, unsigned int* __restrict__ wlist,
    float* __restrict__ out)
{
  __shared__ __align__(16) unsigned short zh[32 * 136];
  __shared__ float scfl[1024];
  __shared__ float szl[32];
  __shared__ float rm1[4][32], rm2[4][32];
  __shared__ int   ri1[4][32];

  const int tid = threadIdx.x;
  const int R0 = blockIdx.x * 32;
  const int b = R0 >> 12, t0 = R0 & 4095;
  const float* zb = z + (size_t)b * 524288;

#pragma unroll
  for (int k = 0; k < 4; ++k) scfl[k * 256 + tid] = scf[k * 256 + tid];
  if (tid < 32) szl[tid] = szf[R0 + tid];

  {                                              // z -> bf16 LDS (no norms here)
    int t = tid & 31;
#pragma unroll
    for (int k = 0; k < 16; ++k) {
      int d = k * 8 + (tid >> 5);
      zh[t * 136 + d] = bf_rne(zb[(size_t)d * 4096 + t0 + t]);
    }
  }
  __syncthreads();

  const int w = tid >> 6, l = tid & 63, lj = l & 15, lg = l >> 4;

  short8 Ah[2][4];
#pragma unroll
  for (int tt = 0; tt < 2; ++tt)
#pragma unroll
    for (int ks = 0; ks < 4; ++ks)
      Ah[tt][ks] = *reinterpret_cast<const short8*>(
          &zh[(tt * 16 + lj) * 136 + ks * 32 + lg * 8]);
  float szr[2][4];
#pragma unroll
  for (int tt = 0; tt < 2; ++tt)
#pragma unroll
    for (int r = 0; r < 4; ++r) szr[tt][r] = szl[tt * 16 + lg * 4 + r];

  float m1[8], m2[8]; int i1[8];
#pragma unroll
  for (int s = 0; s < 8; ++s) { m1[s] = 3.4e38f; m2[s] = 3.4e38f; i1[s] = 0; }

  const unsigned short* pwave = cbf + (size_t)w * 16 * 2048 + (size_t)l * 8;

#pragma unroll 1
  for (int q = 0; q < 4; ++q) {
    f32x4 acc[2][4];
#pragma unroll
    for (int u = 0; u < 4; ++u) {
      acc[0][u] = (f32x4){0.f, 0.f, 0.f, 0.f};
      acc[1][u] = (f32x4){0.f, 0.f, 0.f, 0.f};
      const unsigned short* pg = pwave + (size_t)(q * 4 + u) * 2048;
#pragma unroll
      for (int ks = 0; ks < 4; ++ks) {
        short8 bh = *reinterpret_cast<const short8*>(pg + ks * 512);
        acc[0][u] = __builtin_amdgcn_mfma_f32_16x16x32_bf16(Ah[0][ks], bh, acc[0][u], 0, 0, 0);
        acc[1][u] = __builtin_amdgcn_mfma_f32_16x16x32_bf16(Ah[1][ks], bh, acc[1][u], 0, 0, 0);
      }
    }
    // epilogue: numpy chain fl(fl(sz-2m)+sc), min1/min2, direct dist store
#pragma unroll
    for (int u = 0; u < 4; ++u) {
      const int jj = w * 256 + (q * 4 + u) * 16 + lj;
      const float sc = scfl[jj];
#pragma unroll
      for (int tt = 0; tt < 2; ++tt)
#pragma unroll
        for (int r = 0; r < 4; ++r) {
          float dv = (szr[tt][r] - 2.0f * acc[tt][u][r]) + sc;
          const int s = tt * 4 + r;
          bool lt1 = dv < m1[s];
          float o1 = m1[s];
          m2[s] = lt1 ? o1 : fminf(m2[s], dv);
          m1[s] = lt1 ? dv : o1;
          i1[s] = lt1 ? jj : i1[s];
          out[OFF_DIST + (size_t)(R0 + tt * 16 + lg * 4 + r) * 1024 + jj] = dv;
        }
    }
  }

  // in-wave 16-lane lexicographic (val,idx) reduce, tracking min2
#pragma unroll
  for (int s = 0; s < 8; ++s) {
    float a1 = m1[s]; int ai = i1[s]; float a2 = m2[s];
#pragma unroll
    for (int msk = 1; msk <= 8; msk <<= 1) {
      float b1 = __shfl_xor(a1, msk);
      int   bi = __shfl_xor(ai, msk);
      float b2 = __shfl_xor(a2, msk);
      bool keep = (a1 < b1) || (a1 == b1 && ai < bi);
      float lose = keep ? b1 : a1;
      a2 = fminf(fminf(a2, b2), lose);
      ai = keep ? ai : bi;
      a1 = keep ? a1 : b1;
    }
    if (lj == 0) {
      int t = (s >> 2) * 16 + lg * 4 + (s & 3);
      rm1[w][t] = a1; ri1[w][t] = ai; rm2[w][t] = a2;
    }
  }
  __syncthreads();
  if (tid < 32) {                                // merge 4 waves (j ascending)
    float f1 = rm1[0][tid]; int fi = ri1[0][tid]; float f2 = rm2[0][tid];
#pragma unroll
    for (int ww = 1; ww < 4; ++ww) {
      float b1 = rm1[ww][tid]; int bi = ri1[ww][tid]; float b2 = rm2[ww][tid];
      bool keep = (f1 < b1) || (f1 == b1 && fi < bi);
      float lose = keep ? b1 : f1;
      f2 = fminf(fminf(f2, b2), lose);
      fi = keep ? fi : bi;
      f1 = keep ? f1 : b1;
    }
    int R = R0 + tid;
    out[OFF_CODES + R] = (float)fi;
    if (f2 - f1 <= EPS) {                        // append ambiguous row
      unsigned int pos = atomicAdd(wcnt, 1u);
      wlist[pos] = (unsigned int)R;
    }
  }
}

// ---- z_q + loss (r7-proven structure) ----
__global__ __launch_bounds__(256) void vq_out_kernel(
    const float* __restrict__ z, const float* __restrict__ cb,
    float* __restrict__ out, double* __restrict__ lacc)
{
  __shared__ int ci[128];
  __shared__ float cq[128][129];
  __shared__ double lw[4];
  const int tid = threadIdx.x;
  const int b  = blockIdx.x >> 5;
  const int t0 = (blockIdx.x & 31) * 128;
  const int R0 = b * 4096 + t0;
  if (tid < 128) ci[tid] = (int)out[OFF_CODES + R0 + tid];
  __syncthreads();
  for (int r = 0; r < 128; r += 2) {
    int row = r + (tid >> 7);
    int d = tid & 127;
    cq[row][d] = cb[(size_t)ci[row] * 128 + d];
  }
  __syncthreads();
  double ls = 0.0;
  for (int dp = 0; dp < 128; dp += 2) {
    int d = dp + (tid >> 7);
    int t = tid & 127;
    size_t o = (size_t)b * 524288 + (size_t)d * 4096 + t0 + t;
    float zv = z[o];
    float q = cq[t][d];
    out[o] = zv + (q - zv);                      // straight-through f32 chain
    double dd = (double)q - (double)zv;
    ls += dd * dd;
  }
#pragma unroll
  for (int msk = 1; msk <= 32; msk <<= 1) ls += __shfl_xor(ls, msk);
  if ((tid & 63) == 0) lw[tid >> 6] = ls;
  __syncthreads();
  if (tid == 0) atomicAdd(lacc, lw[0] + lw[1] + lw[2] + lw[3]);
}

// ---- refine: worklist rows -> exact argmin; patch codes, z_q, loss ----
__global__ __launch_bounds__(256) void vq_refine(
    const float* __restrict__ z, const float* __restrict__ cb,
    const float* __restrict__ scf, const float* __restrict__ szf,
    const unsigned int* __restrict__ wcnt, const unsigned int* __restrict__ wlist,
    float* __restrict__ out, double* __restrict__ lacc)
{
  const int w = threadIdx.x >> 6, l = threadIdx.x & 63;
  const unsigned int cnt = *wcnt;
  for (unsigned int i = blockIdx.x * 4 + w; i < cnt; i += 1024) {
    const int R = (int)wlist[i];
    const int b = R >> 12, t = R & 4095;

    const float* drow = out + OFF_DIST + (size_t)R * 1024;
    float v[16];
#pragma unroll
    for (int k = 0; k < 16; ++k) v[k] = drow[k * 64 + l];
    float mn = 3.4e38f;
#pragma unroll
    for (int k = 0; k < 16; ++k) mn = fminf(mn, v[k]);
#pragma unroll
    for (int msk = 1; msk <= 32; msk <<= 1) mn = fminf(mn, __shfl_xor(mn, msk));
    const float thresh = mn + EPS;

    const float zv0f = z[(size_t)b * 524288 + (size_t)l * 4096 + t];
    const float zv1f = z[(size_t)b * 524288 + (size_t)(l + 64) * 4096 + t];
    const double zd0 = (double)zv0f, zd1 = (double)zv1f;
    const float szv = szf[R];

    float bestv = 3.4e38f; int bestj = 1 << 30;
#pragma unroll
    for (int k = 0; k < 16; ++k) {
      unsigned long long msk = __ballot(v[k] <= thresh);
      while (msk) {
        int s = __ffsll((unsigned long long)msk) - 1;
        msk &= msk - 1;
        int jc = k * 64 + s;
        float c0 = cb[(size_t)jc * 128 + l];
        float c1 = cb[(size_t)jc * 128 + 64 + l];
        double m = zd0 * (double)c0 + zd1 * (double)c1;
#pragma unroll
        for (int mm = 1; mm <= 32; mm <<= 1) m += __shfl_xor(m, mm);
        float m32 = (float)m;
        float dvex = (szv - 2.0f * m32) + scf[jc];
        if (dvex < bestv || (dvex == bestv && jc < bestj)) { bestv = dvex; bestj = jc; }
      }
    }

    const int fiOld = (int)out[OFF_CODES + R];
    if (bestj != fiOld) {
      if (l == 0) out[OFF_CODES + R] = (float)bestj;
      float cn0 = cb[(size_t)bestj * 128 + l];
      float cn1 = cb[(size_t)bestj * 128 + 64 + l];
      float co0 = cb[(size_t)fiOld * 128 + l];
      float co1 = cb[(size_t)fiOld * 128 + 64 + l];
      float* zq = out + (size_t)b * 524288 + t;
      zq[(size_t)l * 4096]        = zv0f + (cn0 - zv0f);
      zq[(size_t)(l + 64) * 4096] = zv1f + (cn1 - zv1f);
      double dn0 = (double)cn0 - zd0, dn1 = (double)cn1 - zd1;
      double do0 = (double)co0 - zd0, do1 = (double)co1 - zd1;
      double dl = dn0 * dn0 + dn1 * dn1 - do0 * do0 - do1 * do1;
#pragma unroll
      for (int mm = 1; mm <= 32; mm <<= 1) dl += __shfl_xor(dl, mm);
      if (l == 0) atomicAdd(lacc, dl);
    }
  }
}

__global__ void vq_fin(const double* lacc, float* out) {
  if (threadIdx.x == 0 && blockIdx.x == 0)
    out[OFF_LOSS] = (float)(*lacc * (1.25 / 4194304.0));
}

extern "C" void kernel_launch(void* const* d_in, const int* in_sizes, int n_in,
                              void* d_out, int out_size, void* d_ws, size_t ws_size,
                              hipStream_t stream) {
  const float* z  = (const float*)d_in[0];
  const float* cb = (const float*)d_in[1];
  float* out = (float*)d_out;
  char* ws = (char*)d_ws;
  double* lacc = (double*)(ws + WS_LACC);
  unsigned int* wcnt = (unsigned int*)(ws + WS_WCNT);
  float* scf = (float*)(ws + WS_SCF);
  float* szf = (float*)(ws + WS_SZF);
  unsigned int* wlist = (unsigned int*)(ws + WS_WLST);
  unsigned short* cbf = (unsigned short*)(ws + WS_CBF);

  vq_cbfrag<<<64, 256, 0, stream>>>(cb, cbf, scf, lacc, wcnt);
  vq_szf<<<512, 256, 0, stream>>>(z, szf);
  vq_main<<<1024, 256, 0, stream>>>(z, cbf, scf, szf, wcnt, wlist, out);
  vq_out_kernel<<<256, 256, 0, stream>>>(z, cb, out, lacc);
  vq_refine<<<256, 256, 0, stream>>>(z, cb, scf, szf, wcnt, wlist, out, lacc);
  vq_fin<<<1, 64, 0, stream>>>(lacc, out);
}

// Round 13
// 79.513 us; speedup vs baseline: 1.0984x; 1.0984x over previous
//
#include <hip/hip_runtime.h>

typedef __attribute__((ext_vector_type(8))) short short8;
typedef __attribute__((ext_vector_type(4))) float f32x4;

namespace {
constexpr long long OFF_CODES = 4194304;        // 8*128*4096
constexpr long long OFF_LOSS  = 4227072;        // + 8*4096
constexpr long long OFF_DIST  = 4227073;
constexpr float EPS = 5e-4f;                    // > 2*max bf16-product dist err
// ws byte offsets (max end 532480 — well under proven ~2MB)
constexpr size_t WS_LACC = 0;
constexpr size_t WS_SCF  = 1024;                // 1024 f32
constexpr size_t WS_SZF  = 8192;                // 32768 f32 (ends 139264)
constexpr size_t WS_FLAG = 139264;              // 32768 u32 (ends 270336)
constexpr size_t WS_CBF  = 270336;              // 1024*128 u16 frag-ordered (ends 532480)
}

__device__ __forceinline__ unsigned short bf_rne(float v) {
  unsigned int u = __float_as_uint(v);
  unsigned int r = u + 0x7FFFu + ((u >> 16) & 1u);
  return (unsigned short)(r >> 16);
}

// ---- prep: codebook -> fragment-ordered bf16 + f32 norms; zero lacc ----
// cbf layout: ((g*4 + ks)*64 + lane)*8, g = j-group of 16, lane = (lg,lj),
// element e maps to cb[(g*16+lj)*128 + ks*32 + lg*8 + e].
__global__ __launch_bounds__(256) void vq_cbfrag(
    const float* __restrict__ cb, unsigned short* __restrict__ cbf,
    float* __restrict__ scf, double* lacc)
{
  __shared__ double pn[4][16];
  const int g = blockIdx.x;
  const int tid = threadIdx.x;
  const int ks = tid >> 6, l = tid & 63, lg = l >> 4, lj = l & 15;
  const float* src = cb + (size_t)(g * 16 + lj) * 128 + ks * 32 + lg * 8;
  double s = 0.0;
  short8 h;
#pragma unroll
  for (int e = 0; e < 8; ++e) {
    float v = src[e];
    float q = v * v;                             // f32 square (numpy chain)
    s += (double)q;
    h[e] = (short)bf_rne(v);
  }
  *reinterpret_cast<short8*>(cbf + (size_t)g * 2048 + (size_t)tid * 8) = h;
  s += __shfl_xor(s, 16);                        // reduce over lg (same lj)
  s += __shfl_xor(s, 32);
  if (lg == 0) pn[ks][lj] = s;
  __syncthreads();
  if (tid < 16)
    scf[g * 16 + tid] = (float)(pn[0][tid] + pn[1][tid] + pn[2][tid] + pn[3][tid]);
  if (blockIdx.x == 0 && tid == 0) *lacc = 0.0;
}

// ---- z row norms (f64 of f32 squares), coalesced [d][t] tile walk ----
__global__ __launch_bounds__(256) void vq_szf(
    const float* __restrict__ z, float* __restrict__ szf)
{
  __shared__ double pn[64][4];
  const int tid = threadIdx.x;
  const int R0 = blockIdx.x * 64;
  const int b = R0 >> 12, t0 = R0 & 4095;
  const int t = tid & 63, dg = tid >> 6;
  const float* zp = z + (size_t)b * 524288 + (size_t)dg * 32 * 4096 + t0 + t;
  double s = 0.0;
#pragma unroll
  for (int d = 0; d < 32; ++d) {
    float v = zp[(size_t)d * 4096];
    float q = v * v;
    s += (double)q;
  }
  pn[t][dg] = s;
  __syncthreads();
  if (tid < 64)
    szf[R0 + tid] = (float)(pn[tid][0] + pn[tid][1] + pn[tid][2] + pn[tid][3]);
}

// ---- main: 32 rows x 1024 j per block; coalesced frag B; quartered acc ----
__global__ __launch_bounds__(256, 4) void vq_main(
    const float* __restrict__ z, const unsigned short* __restrict__ cbf,
    const float* __restrict__ scf, const float* __restrict__ szf,
    unsigned int* __restrict__ flags, float* __restrict__ out)
{
  __shared__ __align__(16) unsigned short zh[32 * 136];
  __shared__ float scfl[1024];
  __shared__ float szl[32];
  __shared__ float rm1[4][32], rm2[4][32];
  __shared__ int   ri1[4][32];

  const int tid = threadIdx.x;
  const int R0 = blockIdx.x * 32;
  const int b = R0 >> 12, t0 = R0 & 4095;
  const float* zb = z + (size_t)b * 524288;

#pragma unroll
  for (int k = 0; k < 4; ++k) scfl[k * 256 + tid] = scf[k * 256 + tid];
  if (tid < 32) szl[tid] = szf[R0 + tid];

  {                                              // z -> bf16 LDS (no norms here)
    int t = tid & 31;
#pragma unroll
    for (int k = 0; k < 16; ++k) {
      int d = k * 8 + (tid >> 5);
      zh[t * 136 + d] = bf_rne(zb[(size_t)d * 4096 + t0 + t]);
    }
  }
  __syncthreads();

  const int w = tid >> 6, l = tid & 63, lj = l & 15, lg = l >> 4;

  short8 Ah[2][4];
#pragma unroll
  for (int tt = 0; tt < 2; ++tt)
#pragma unroll
    for (int ks = 0; ks < 4; ++ks)
      Ah[tt][ks] = *reinterpret_cast<const short8*>(
          &zh[(tt * 16 + lj) * 136 + ks * 32 + lg * 8]);
  float szr[2][4];
#pragma unroll
  for (int tt = 0; tt < 2; ++tt)
#pragma unroll
    for (int r = 0; r < 4; ++r) szr[tt][r] = szl[tt * 16 + lg * 4 + r];

  float m1[8], m2[8]; int i1[8];
#pragma unroll
  for (int s = 0; s < 8; ++s) { m1[s] = 3.4e38f; m2[s] = 3.4e38f; i1[s] = 0; }

  const unsigned short* pwave = cbf + (size_t)w * 16 * 2048 + (size_t)l * 8;

#pragma unroll 1
  for (int q = 0; q < 4; ++q) {
    f32x4 acc[2][4];
#pragma unroll
    for (int u = 0; u < 4; ++u) {
      acc[0][u] = (f32x4){0.f, 0.f, 0.f, 0.f};
      acc[1][u] = (f32x4){0.f, 0.f, 0.f, 0.f};
      const unsigned short* pg = pwave + (size_t)(q * 4 + u) * 2048;
#pragma unroll
      for (int ks = 0; ks < 4; ++ks) {
        short8 bh = *reinterpret_cast<const short8*>(pg + ks * 512); // (ks*64)*8
        acc[0][u] = __builtin_amdgcn_mfma_f32_16x16x32_bf16(Ah[0][ks], bh, acc[0][u], 0, 0, 0);
        acc[1][u] = __builtin_amdgcn_mfma_f32_16x16x32_bf16(Ah[1][ks], bh, acc[1][u], 0, 0, 0);
      }
    }
    // epilogue: numpy chain fl(fl(sz-2m)+sc), min1/min2, dist store
#pragma unroll
    for (int u = 0; u < 4; ++u) {
      const int jj = w * 256 + (q * 4 + u) * 16 + lj;
      const float sc = scfl[jj];
#pragma unroll
      for (int tt = 0; tt < 2; ++tt)
#pragma unroll
        for (int r = 0; r < 4; ++r) {
          float dv = (szr[tt][r] - 2.0f * acc[tt][u][r]) + sc;
          const int s = tt * 4 + r;
          bool lt1 = dv < m1[s];
          float o1 = m1[s];
          m2[s] = lt1 ? o1 : fminf(m2[s], dv);
          m1[s] = lt1 ? dv : o1;
          i1[s] = lt1 ? jj : i1[s];
          out[OFF_DIST + (size_t)(R0 + tt * 16 + lg * 4 + r) * 1024 + jj] = dv;
        }
    }
  }

  // in-wave 16-lane lexicographic (val,idx) reduce, tracking min2
#pragma unroll
  for (int s = 0; s < 8; ++s) {
    float a1 = m1[s]; int ai = i1[s]; float a2 = m2[s];
#pragma unroll
    for (int msk = 1; msk <= 8; msk <<= 1) {
      float b1 = __shfl_xor(a1, msk);
      int   bi = __shfl_xor(ai, msk);
      float b2 = __shfl_xor(a2, msk);
      bool keep = (a1 < b1) || (a1 == b1 && ai < bi);
      float lose = keep ? b1 : a1;
      a2 = fminf(fminf(a2, b2), lose);
      ai = keep ? ai : bi;
      a1 = keep ? a1 : b1;
    }
    if (lj == 0) {
      int t = (s >> 2) * 16 + lg * 4 + (s & 3);
      rm1[w][t] = a1; ri1[w][t] = ai; rm2[w][t] = a2;
    }
  }
  __syncthreads();
  if (tid < 32) {                                // merge 4 waves (j ascending)
    float f1 = rm1[0][tid]; int fi = ri1[0][tid]; float f2 = rm2[0][tid];
#pragma unroll
    for (int ww = 1; ww < 4; ++ww) {
      float b1 = rm1[ww][tid]; int bi = ri1[ww][tid]; float b2 = rm2[ww][tid];
      bool keep = (f1 < b1) || (f1 == b1 && fi < bi);
      float lose = keep ? b1 : f1;
      f2 = fminf(fminf(f2, b2), lose);
      fi = keep ? fi : bi;
      f1 = keep ? f1 : b1;
    }
    int R = R0 + tid;
    out[OFF_CODES + R] = (float)fi;
    flags[R] = (f2 - f1 <= EPS) ? 1u : 0u;
  }
}

// ---- refine: flagged rows -> exact f64 dot + exact f32 chain, lex argmin ----
__global__ __launch_bounds__(256) void vq_refine(
    const float* __restrict__ z, const float* __restrict__ cb,
    const float* __restrict__ scf, const float* __restrict__ szf,
    const unsigned int* __restrict__ flags, float* __restrict__ out)
{
  const int w = threadIdx.x >> 6, l = threadIdx.x & 63;
  const int R = blockIdx.x * 4 + w;
  if (!flags[R]) return;
  const int b = R >> 12, t = R & 4095;

  const float* drow = out + OFF_DIST + (size_t)R * 1024;
  float v[16];
#pragma unroll
  for (int k = 0; k < 16; ++k) v[k] = drow[k * 64 + l];
  float mn = 3.4e38f;
#pragma unroll
  for (int k = 0; k < 16; ++k) mn = fminf(mn, v[k]);
#pragma unroll
  for (int msk = 1; msk <= 32; msk <<= 1) mn = fminf(mn, __shfl_xor(mn, msk));
  const float thresh = mn + EPS;

  const double zd0 = (double)z[(size_t)b * 524288 + (size_t)l * 4096 + t];
  const double zd1 = (double)z[(size_t)b * 524288 + (size_t)(l + 64) * 4096 + t];
  const float szv = szf[R];

  float bestv = 3.4e38f; int bestj = 1 << 30;
#pragma unroll
  for (int k = 0; k < 16; ++k) {
    unsigned long long msk = __ballot(v[k] <= thresh);
    while (msk) {
      int s = __ffsll((unsigned long long)msk) - 1;
      msk &= msk - 1;
      int jc = k * 64 + s;
      float c0 = cb[(size_t)jc * 128 + l];
      float c1 = cb[(size_t)jc * 128 + 64 + l];
      double m = zd0 * (double)c0 + zd1 * (double)c1;
#pragma unroll
      for (int mm = 1; mm <= 32; mm <<= 1) m += __shfl_xor(m, mm);
      float m32 = (float)m;
      float dvex = (szv - 2.0f * m32) + scf[jc];
      if (dvex < bestv || (dvex == bestv && jc < bestj)) { bestv = dvex; bestj = jc; }
    }
  }
  if (l == 0) out[OFF_CODES + R] = (float)bestj;
}

// ---- z_q + loss ----
__global__ __launch_bounds__(256) void vq_out_kernel(
    const float* __restrict__ z, const float* __restrict__ cb,
    float* __restrict__ out, double* __restrict__ lacc)
{
  __shared__ int ci[128];
  __shared__ float cq[128][129];
  __shared__ double lw[4];
  const int tid = threadIdx.x;
  const int b  = blockIdx.x >> 5;
  const int t0 = (blockIdx.x & 31) * 128;
  const int R0 = b * 4096 + t0;
  if (tid < 128) ci[tid] = (int)out[OFF_CODES + R0 + tid];
  __syncthreads();
  for (int r = 0; r < 128; r += 2) {
    int row = r + (tid >> 7);
    int d = tid & 127;
    cq[row][d] = cb[(size_t)ci[row] * 128 + d];
  }
  __syncthreads();
  double ls = 0.0;
  for (int dp = 0; dp < 128; dp += 2) {
    int d = dp + (tid >> 7);
    int t = tid & 127;
    size_t o = (size_t)b * 524288 + (size_t)d * 4096 + t0 + t;
    float zv = z[o];
    float q = cq[t][d];
    out[o] = zv + (q - zv);                      // straight-through f32 chain
    double dd = (double)q - (double)zv;
    ls += dd * dd;
  }
#pragma unroll
  for (int msk = 1; msk <= 32; msk <<= 1) ls += __shfl_xor(ls, msk);
  if ((tid & 63) == 0) lw[tid >> 6] = ls;
  __syncthreads();
  if (tid == 0) atomicAdd(lacc, lw[0] + lw[1] + lw[2] + lw[3]);
}

__global__ void vq_fin(const double* lacc, float* out) {
  if (threadIdx.x == 0 && blockIdx.x == 0)
    out[OFF_LOSS] = (float)(*lacc * (1.25 / 4194304.0));
}

extern "C" void kernel_launch(void* const* d_in, const int* in_sizes, int n_in,
                              void* d_out, int out_size, void* d_ws, size_t ws_size,
                              hipStream_t stream) {
  const float* z  = (const float*)d_in[0];
  const float* cb = (const float*)d_in[1];
  float* out = (float*)d_out;
  char* ws = (char*)d_ws;
  double* lacc = (double*)(ws + WS_LACC);
  float* scf = (float*)(ws + WS_SCF);
  float* szf = (float*)(ws + WS_SZF);
  unsigned int* flags = (unsigned int*)(ws + WS_FLAG);
  unsigned short* cbf = (unsigned short*)(ws + WS_CBF);

  vq_cbfrag<<<64, 256, 0, stream>>>(cb, cbf, scf, lacc);
  vq_szf<<<512, 256, 0, stream>>>(z, szf);
  vq_main<<<1024, 256, 0, stream>>>(z, cbf, scf, szf, flags, out);
  vq_refine<<<8192, 256, 0, stream>>>(z, cb, scf, szf, flags, out);
  vq_out_kernel<<<256, 256, 0, stream>>>(z, cb, out, lacc);
  vq_fin<<<1, 64, 0, stream>>>(lacc, out);
}